// Round 1
// baseline (160.653 us; speedup 1.0000x reference)
//
#include <hip/hip_runtime.h>
#include <math.h>

// SpectralConv2d: out = idht2( mix( dht2(x)[:, :, :32, :32], W ) ) / S^2
// x:  [32][64][128][128] f32   weights1: [64][64][32][32] f32
// out:[32][64][128][128] f32
//
// M is the recursive pseudo-Hartley operator (NOT plain cas(2pi kn/N)):
//   M[k,n] = prod over levels (size Nj = 128,64,...,2):
//     if bit_j(n): (k_j < Nj/2 ? +1 : -1) * cas(2*pi*(k_j mod Nj/2)/Nj), else 1
//     with k_{j+1} = k_j mod (Nj/2).

#define SS   128
#define MD   32
#define NBAT 32
#define CI   64
#define CO   64

#define TWO_PI 6.2831853071795864769

// ws layout (floats):
//   M  [128][128] at 0        (M[k][n])
//   MT [128][128] at 16384    (MT[n][k] = M[k][n])
//   Xh [2048][32][32] at 32768
//   blk[2048][32][32] after Xh
static const size_t OFF_M   = 0;
static const size_t OFF_MT  = 16384;
static const size_t OFF_XH  = 32768;
static const size_t OFF_BLK = 32768 + (size_t)2048 * 1024;

__global__ void k_build(float* __restrict__ M, float* __restrict__ MT) {
    int idx = blockIdx.x * 256 + threadIdx.x;   // 16384 entries
    int k = idx >> 7, n = idx & 127;
    float prod = 1.f;
    int kk = k, nn = n;
    for (int Nj = SS; Nj > 1; Nj >>= 1) {
        int half = Nj >> 1;
        int k1 = kk & (half - 1);
        if (nn & 1) {
            double ang = (TWO_PI / (double)Nj) * (double)k1;
            float cas = (float)(cos(ang) + sin(ang));
            prod *= (kk < half) ? cas : -cas;
        }
        kk = k1;
        nn >>= 1;
    }
    M[idx] = prod;
    MT[n * 128 + k] = prod;
}

// Forward: per (b,c) block: Xh[k][l] = sum_{h,w} M[k][h]*M[l][w]*x[h][w], k,l<32
__global__ __launch_bounds__(256) void k_fwd(const float* __restrict__ x,
                                             const float* __restrict__ MT,
                                             float* __restrict__ Xh) {
    const int bc = blockIdx.x;
    const float* xp = x + (size_t)bc * (SS * SS);
    const int t = threadIdx.x;
    __shared__ float Ys[MD][SS + 1];   // Y[k][w], padded: bank = (k+w)%32

    // Phase 1: Y[k][w] = sum_h M[k][h] * x[h][w]
    // lane -> w; wave-uniform kh picks k half; M via uniform s_load of MT rows.
    const int w  = t & 127;
    const int kh = __builtin_amdgcn_readfirstlane(t >> 7);   // 0,0,1,1 per wave
    {
        float acc[16];
#pragma unroll
        for (int j = 0; j < 16; ++j) acc[j] = 0.f;
#pragma unroll 4
        for (int h = 0; h < SS; ++h) {
            float xv = xp[h * SS + w];                  // coalesced, L1 reuse x2
            const float* mrow = MT + h * 128 + kh * 16; // uniform -> s_load
#pragma unroll
            for (int j = 0; j < 16; ++j)
                acc[j] = fmaf(mrow[j], xv, acc[j]);
        }
#pragma unroll
        for (int j = 0; j < 16; ++j) Ys[kh * 16 + j][w] = acc[j];
    }
    __syncthreads();

    // Phase 2: Z[k][l] = sum_w Y[k][w] * M[l][w];  M[l][w] = MT[w*128+l]
    // lane -> k (upper 32 lanes duplicate); l-set uniform per wave (s_load).
    const int k   = t & 31;
    const int dup = (t >> 5) & 1;
    const int wid = __builtin_amdgcn_readfirstlane(t >> 6);  // 0..3
    float z[8];
#pragma unroll
    for (int j = 0; j < 8; ++j) z[j] = 0.f;
#pragma unroll 8
    for (int ww = 0; ww < SS; ++ww) {
        float yv = Ys[k][ww];                        // conflict-free: (k+ww)%32
        const float* mcol = MT + ww * 128 + wid * 8; // uniform -> s_load
#pragma unroll
        for (int j = 0; j < 8; ++j)
            z[j] = fmaf(mcol[j], yv, z[j]);
    }
    if (dup == 0) {
        float* outp = Xh + (size_t)bc * (MD * MD) + k * MD + wid * 8;
#pragma unroll
        for (int j = 0; j < 8; ++j) outp[j] = z[j];
    }
}

// Mix: blk[b][o][xy] = sum_i Xh[b][i][xy]*We[i][o][xy] + Xh[b][i][nxy]*Wo[i][o][xy]
// We = 0.5*(w[xy]+w[nxy]), Wo = 0.5*(w[xy]-w[nxy]).
// lane -> xy (all global accesses coalesced; neg-freq is an intra-line permute).
__global__ __launch_bounds__(256) void k_mix(const float* __restrict__ Xh,
                                             const float* __restrict__ wgt,
                                             float* __restrict__ blk) {
    const int bid = blockIdx.x;     // 256 blocks = 4 xyc * 4 bg * 16 og
    const int xyc = bid & 3;
    const int bg  = (bid >> 2) & 3;
    const int og  = bid >> 4;
    const int t   = threadIdx.x;
    const int xy  = xyc * 256 + t;
    const int xm  = xy >> 5, ym = xy & 31;
    const int nxy = ((32 - xm) & 31) * 32 + ((32 - ym) & 31);

    float acc[8][4];
#pragma unroll
    for (int bi = 0; bi < 8; ++bi)
#pragma unroll
        for (int oi = 0; oi < 4; ++oi) acc[bi][oi] = 0.f;

#pragma unroll 2
    for (int i = 0; i < CI; ++i) {
        float x1[8], x1n[8];
#pragma unroll
        for (int bi = 0; bi < 8; ++bi) {
            size_t base = ((size_t)((bg * 8 + bi) * CI + i)) * 1024;
            x1[bi]  = Xh[base + xy];
            x1n[bi] = Xh[base + nxy];
        }
#pragma unroll
        for (int oi = 0; oi < 4; ++oi) {
            size_t wb = ((size_t)(i * CO + og * 4 + oi)) * 1024;
            float wv = wgt[wb + xy];
            float wn = wgt[wb + nxy];
            float we = 0.5f * (wv + wn);
            float wo = 0.5f * (wv - wn);
#pragma unroll
            for (int bi = 0; bi < 8; ++bi)
                acc[bi][oi] = fmaf(x1[bi], we, fmaf(x1n[bi], wo, acc[bi][oi]));
        }
    }
#pragma unroll
    for (int bi = 0; bi < 8; ++bi)
#pragma unroll
        for (int oi = 0; oi < 4; ++oi)
            blk[((size_t)((bg * 8 + bi) * CO + og * 4 + oi)) * 1024 + xy] = acc[bi][oi];
}

// Inverse: per (b,o) block:
//   T[r][l]   = (1/16384) * sum_{h<32} M[r][h] * blk[h][l]
//   out[r][c] = sum_{l<32} T[r][l] * M[c][l]
__global__ __launch_bounds__(256) void k_inv(const float* __restrict__ blk,
                                             const float* __restrict__ M,
                                             const float* __restrict__ MT,
                                             float* __restrict__ out) {
    const int bo = blockIdx.x;
    const int t  = threadIdx.x;
    __shared__ float smem[8448];       // Mcs[128][33] | Ts[128][33]; reused as outS[128][65]
    float* Mcs  = smem;
    float* Ts   = smem + 4224;
    float* outS = smem;

    // stage Mcs[r][h] = M[r][h<32] * 1/16384 (coalesced 128B row chunks)
#pragma unroll
    for (int j = 0; j < 16; ++j) {
        int idx = t + j * 256;
        int r = idx >> 5, h = idx & 31;
        Mcs[r * 33 + h] = M[r * 128 + h] * (1.f / 16384.f);
    }
    __syncthreads();

    const int r  = t & 127;
    const int rh = __builtin_amdgcn_readfirstlane(t >> 7);   // 0 or 1

    // T phase: lane -> r (Mcs per-lane, conflict-free), blk rows via s_load.
    {
        const float* bp = blk + (size_t)bo * (MD * MD);
        float acc[16];
#pragma unroll
        for (int j = 0; j < 16; ++j) acc[j] = 0.f;
#pragma unroll 4
        for (int h = 0; h < MD; ++h) {
            float mc = Mcs[r * 33 + h];
            const float* brow = bp + h * MD + rh * 16;   // uniform -> s_load_x8
#pragma unroll
            for (int j = 0; j < 16; ++j)
                acc[j] = fmaf(brow[j], mc, acc[j]);
        }
#pragma unroll
        for (int j = 0; j < 16; ++j) Ts[r * 33 + rh * 16 + j] = acc[j];
    }
    __syncthreads();

    // out phase: out[r][c] = sum_l Ts[r][l] * MT[l*128 + c]; c-set (64) uniform.
    float acc[64];
#pragma unroll
    for (int j = 0; j < 64; ++j) acc[j] = 0.f;
#pragma unroll 2
    for (int l = 0; l < MD; ++l) {
        float tv = Ts[r * 33 + l];                   // per-lane, (r+l)%32 banks
        const float* mt = MT + l * 128 + rh * 64;    // uniform -> s_load_x16
#pragma unroll
        for (int j = 0; j < 64; ++j)
            acc[j] = fmaf(mt[j], tv, acc[j]);
    }

    // LDS-transpose epilogue for coalesced stores (two rounds: c-half 0, 1).
    float* op = out + (size_t)bo * (SS * SS);
    for (int rr = 0; rr < 2; ++rr) {
        __syncthreads();               // prior reads of smem done
        if (rh == rr) {
#pragma unroll
            for (int j = 0; j < 64; ++j) outS[r * 65 + j] = acc[j];
        }
        __syncthreads();
        const int cc = t & 63;
        const int r0 = t >> 6;
#pragma unroll
        for (int j = 0; j < 32; ++j) {
            int rrow = r0 + 4 * j;
            op[rrow * SS + rr * 64 + cc] = outS[rrow * 65 + cc];
        }
    }
}

extern "C" void kernel_launch(void* const* d_in, const int* in_sizes, int n_in,
                              void* d_out, int out_size, void* d_ws, size_t ws_size,
                              hipStream_t stream) {
    const float* x   = (const float*)d_in[0];
    const float* wgt = (const float*)d_in[1];
    float* outp = (float*)d_out;
    float* ws   = (float*)d_ws;

    float* M   = ws + OFF_M;
    float* MT  = ws + OFF_MT;
    float* Xh  = ws + OFF_XH;
    float* blk = ws + OFF_BLK;

    k_build<<<64, 256, 0, stream>>>(M, MT);
    k_fwd  <<<2048, 256, 0, stream>>>(x, MT, Xh);
    k_mix  <<<256, 256, 0, stream>>>(Xh, wgt, blk);
    k_inv  <<<2048, 256, 0, stream>>>(blk, M, MT, outp);
}